// Round 10
// baseline (2388.838 us; speedup 1.0000x reference)
//
#include <hip/hip_runtime.h>

// KalmanNet recurrent step, MFMA fp16, r10: two independent blocks per CU.
//
// r6-r9 post-mortem: three intra-wave scheduling rounds (pinned prefetch,
// spill-free shrink, global_load_lds + counted vmcnt) all plateau at
// 1350-1420 us. Compute chain per step is ~7 us vs 43 us wall: the
// serializer is the 5-phase barrier chain of a SINGLE resident block --
// at every barrier all waves wait out the slowest latency chain with
// nothing else to run. r10 restores block-level TLP: BR 32->16 (one
// 16x16 m-tile), 512 threads (8 waves), LDS ~51 KB -> 2 blocks/CU
// (grid 512). When block A stalls at a barrier/miss, block B issues.
// All staging/vmcnt/sched_barrier machinery removed: plain loads,
// full unroll, ~40-reg live set, compiler schedules freely.
//
// Work split (8 waves): gates 13 j-tiles: waves 0-4 own {w, w+8},
// waves 5-7 own {w}; W2 20 tiles: {w, w+8} + {w+16} for w<4; W1 30
// tiles: {w, w+8, w+16} + {w+24} for w<6; W3: waves 0,1 (k-halves).
// GRU in registers (each wave's C/D tiles cover all 4 gate groups for
// its j-columns); h lives in A-fragment slots k=480+j. State in parity
// LDS (r8). Bias folding: W1 ones-row k=8 -> b1; h-pad k=680==1.0
// carries b2 via g_w2 row 200. NO numerics change (absmax 4.88e-4).
//
// Fragment maps (verified r2-r9): A/B k = kt*32 + (lane>>4)*8 + i,
// A row / B col = lane&15; C/D col = lane&15, row = (lane>>4)*4 + reg.

namespace {

constexpr int T_STEPS = 32;
constexpr int BATCH   = 8192;
constexpr int H1      = 480;
constexpr int HID     = 200;
constexpr int H2      = 320;
constexpr int BR      = 16;    // batch rows per block (1 MFMA m-tile)
constexpr int NTHR    = 512;   // 8 waves; 2 blocks/CU
constexpr int KTG     = 22;    // gates K tiles (704 = 480 a1 + 224 h/pad)
constexpr int NTG     = 52;    // 4 groups x 13 real j-tiles
constexpr int NTW1    = 30;    // W1 real col tiles (480/16)
constexpr int NT2     = 20;    // W2 real col tiles (320/16)
constexpr int KT2     = 7;     // W2 K tiles (224)
constexpr int KT3     = 10;    // W3 K tiles (320)

using f16x8 = __attribute__((ext_vector_type(8))) _Float16;
using f32x4 = __attribute__((ext_vector_type(4))) float;

__device__ _Float16 g_w1[NTW1 * 512];          // [nt][lane][8], k=8 row = b1
__device__ _Float16 g_wcat[NTG * KTG * 512];   // [grp*13+tile][kt][lane][8]
__device__ _Float16 g_w2[NT2 * KT2 * 512];     // [nt][kt][lane][8], k_h=200 = b2
__device__ _Float16 g_w3[KT3 * 512];           // [kt][lane][8], cols 8..15 = 0

#define MFMA16(A, B, C) __builtin_amdgcn_mfma_f32_16x16x32_f16((A), (B), (C), 0, 0, 0)

__device__ __forceinline__ float sigmoid_(float x) { return 1.f / (1.f + __expf(-x)); }
__device__ __forceinline__ float tanh_(float x) {
  x = fminf(fmaxf(x, -15.f), 15.f);
  const float e = __expf(-2.f * x);
  return (1.f - e) / (1.f + e);
}
__device__ __forceinline__ f16x8 f16x8_zero() {
  f16x8 v;
#pragma unroll
  for (int i = 0; i < 8; ++i) v[i] = (_Float16)0.f;
  return v;
}

// element (k, r) -> flat half index in A-fragment LDS layout (BR=16)
// [kt][lane = ((k&31)>>3)*16 + (r&15)][i = k&7]
__device__ __forceinline__ int afrag_off(int k, int r) {
  const int kt = k >> 5, kk = k & 31;
  return kt * 512 + ((((kk >> 3) << 4) | (r & 15)) * 8) + (kk & 7);
}

// ---------------- weight pre-pack ----------------
__global__ __launch_bounds__(256) void prep_kernel(
    const float* __restrict__ W1, const float* __restrict__ b1,
    const float* __restrict__ Wg, const float* __restrict__ Ug,
    const float* __restrict__ W2, const float* __restrict__ b2,
    const float* __restrict__ W3) {
  const int idx = blockIdx.x * 256 + threadIdx.x;
  constexpr int TOTW1 = NTW1 * 512;
  constexpr int TOT1  = NTG * KTG * 512;
  constexpr int TOT2  = NT2 * KT2 * 512;
  constexpr int TOT3  = KT3 * 512;
  if (idx < TOTW1) {
    const int i = idx & 7, l = (idx >> 3) & 63, nt = idx >> 9;
    const int g = l >> 4, c = l & 15;
    const int k = g * 8 + i, col = nt * 16 + c;   // col < 480 always
    float wv = 0.f;
    if (k < 8) wv = W1[k * H1 + col];
    else if (k == 8) wv = b1[col];
    g_w1[idx] = (_Float16)wv;
  } else if (idx < TOTW1 + TOT1) {
    const int id = idx - TOTW1;
    const int i = id & 7, l = (id >> 3) & 63, nk = id >> 9;
    const int kt = nk % KTG, nt = nk / KTG;
    const int g = l >> 4, c = l & 15;
    const int k = kt * 32 + g * 8 + i;        // 0..703
    const int grp = nt / 13;                  // 0=z 1=r 2=xh 3=hh
    const int jj = (nt - grp * 13) * 16 + c;  // 0..207
    float wv = 0.f;
    if (jj < HID) {
      if (grp == 0) {
        if (k < H1) wv = Wg[k * 600 + jj];
        else if (k < H1 + HID) wv = Ug[(k - H1) * 600 + jj];
      } else if (grp == 1) {
        if (k < H1) wv = Wg[k * 600 + 200 + jj];
        else if (k < H1 + HID) wv = Ug[(k - H1) * 600 + 200 + jj];
      } else if (grp == 2) {
        if (k < H1) wv = Wg[k * 600 + 400 + jj];           // xh: a1 rows only
      } else {
        if (k >= H1 && k < H1 + HID) wv = Ug[(k - H1) * 600 + 400 + jj];  // hh
      }
    }
    g_wcat[id] = (_Float16)wv;
  } else if (idx < TOTW1 + TOT1 + TOT2) {
    const int id = idx - TOTW1 - TOT1;
    const int i = id & 7, l = (id >> 3) & 63, nk = id >> 9;
    const int kt = nk % KT2, nt = nk / KT2;
    const int g = l >> 4, c = l & 15;
    const int k = kt * 32 + g * 8 + i;        // 0..223
    const int col = nt * 16 + c;              // 0..319 (all real)
    float wv = 0.f;
    if (k < HID) wv = W2[k * H2 + col];
    else if (k == 200) wv = b2[col];          // ones-row at k_h=200 (k=680)
    g_w2[id] = (_Float16)wv;
  } else if (idx < TOTW1 + TOT1 + TOT2 + TOT3) {
    const int id = idx - TOTW1 - TOT1 - TOT2;
    const int i = id & 7, l = (id >> 3) & 63, kt = id >> 9;
    const int g = l >> 4, c = l & 15;
    const int k = kt * 32 + g * 8 + i;        // 0..319
    g_w3[id] = (_Float16)((c < 8) ? W3[k * 8 + c] : 0.f);
  }
}

// ---------------- main recurrent kernel ----------------
__global__
__attribute__((amdgpu_flat_work_group_size(NTHR, NTHR)))
__attribute__((amdgpu_waves_per_eu(4, 4)))
void knet_kernel(
    const float* __restrict__ y,    // [T,B,2]
    const float* __restrict__ Fm,   // [4,4]
    const float* __restrict__ Hm,   // [2,4]
    const float* __restrict__ bg,   // [2,600]
    const float* __restrict__ b3,   // [8]
    const float* __restrict__ hn0,  // [B,200]
    float* __restrict__ out)        // [T,B,4]
{
  // A-fragments of x_cat = [a1(480) | h(200) | 1.0 @680 | 0-pad]; a2 reuses
  // slots 0..9 between phase E and phase F.
  __shared__ alignas(16) _Float16 sAhi[KTG * 512];   // 22528 B
  __shared__ alignas(16) _Float16 sAlo[KTG * 512];   // 22528 B
  __shared__ alignas(16) float s_in8T[8][BR];
  __shared__ alignas(16) float s_kgp[2][BR][8];      // KG k-half partials
  __shared__ alignas(16) float s_bias[4][HID];
  __shared__ alignas(16) float s_fh[32];             // Fm[16], Hm[8]
  __shared__ alignas(16) float s_b3[8];
  // persistent per-row filter state, double-buffered by t-parity (r8)
  __shared__ alignas(16) float s_prior2[2][BR][4];
  __shared__ alignas(16) float s_d2[2][BR][2];

  const int tid  = threadIdx.x;
  const int lane = tid & 63;
  const int wid  = __builtin_amdgcn_readfirstlane(tid >> 6);  // 0..7
  const int row0 = blockIdx.x * BR;
  const int rl   = lane & 15;
  const int g4   = (lane >> 4) << 2;
  const int ab   = lane * 8;

  // ---- init ----
  if (tid < HID) {
    s_bias[0][tid] = bg[tid]       + bg[600 + tid];   // z
    s_bias[1][tid] = bg[200 + tid] + bg[800 + tid];   // r
    s_bias[2][tid] = bg[400 + tid];                   // xh (input bias)
    s_bias[3][tid] = bg[1000 + tid];                  // hh (recurrent bias)
  }
  if (tid < 16) s_fh[tid] = Fm[tid];
  else if (tid < 24) s_fh[tid] = Hm[tid - 16];
  if (tid < 8) s_b3[tid] = b3[tid];
  if (tid < BR * 4) s_prior2[0][tid >> 2][tid & 3] = 0.f;
  if (tid < BR * 2) s_d2[0][tid >> 1][tid & 1] = 0.f;
  for (int e = tid; e < HID * BR; e += NTHR) {
    const int j = e >> 4, r = e & 15;
    const float h0 = hn0[(size_t)(row0 + r) * HID + j];
    const int off = afrag_off(480 + j, r);
    const _Float16 hi = (_Float16)h0;
    sAhi[off] = hi;
    sAlo[off] = (_Float16)(h0 - (float)hi);
  }
  if (tid < 24 * BR) {   // k 680..703: 1.0 then zeros
    const int k = 680 + (tid >> 4), r = tid & 15;
    const int off = afrag_off(k, r);
    sAhi[off] = (_Float16)((k == 680) ? 1.f : 0.f);
    sAlo[off] = (_Float16)0.f;
  }
  __syncthreads();

  for (int t = 0; t < T_STEPS; ++t) {
    const int p = t & 1;
    // ================= phase 1: F2(t-1) + A(t) + W1-GEMM(t) =================
    {
      float post[4] = {0.f, 0.f, 0.f, 0.f};
      if (t > 0) {
        float kg[8];
#pragma unroll
        for (int cc = 0; cc < 8; ++cc)
          kg[cc] = s_kgp[0][rl][cc] + s_kgp[1][rl][cc] + s_b3[cc];
        const float pd0 = s_d2[p][rl][0], pd1 = s_d2[p][rl][1];
#pragma unroll
        for (int m = 0; m < 4; ++m)
          post[m] = s_prior2[p][rl][m] + kg[2 * m] * pd0 + kg[2 * m + 1] * pd1;
        if (wid == 0 && lane < BR) {
          float4 o; o.x = post[0]; o.y = post[1]; o.z = post[2]; o.w = post[3];
          *(float4*)&out[((size_t)(t - 1) * BATCH + row0 + rl) * 4] = o;
        }
      }
      // ---- A: prior / innovation / features (redundant per wave) ----
      float opri[4], np[4];
#pragma unroll
      for (int m = 0; m < 4; ++m) opri[m] = s_prior2[p][rl][m];
#pragma unroll
      for (int m = 0; m < 4; ++m) {
        float s = 0.f;
#pragma unroll
        for (int j = 0; j < 4; ++j) s += s_fh[m * 4 + j] * post[j];
        np[m] = s;
      }
      float m0 = 0.f, m1 = 0.f;
#pragma unroll
      for (int m = 0; m < 4; ++m) { m0 += s_fh[16 + m] * np[m]; m1 += s_fh[20 + m] * np[m]; }
      const float2 yv = *(const float2*)&y[((size_t)t * BATCH + row0 + rl) * 2];
      const float d0 = yv.x - m0;
      const float d1 = yv.y - m1;
      float dx[4], ssx = 0.f;
#pragma unroll
      for (int m = 0; m < 4; ++m) { dx[m] = post[m] - opri[m]; ssx += dx[m] * dx[m]; }
      const float idx_ = rsqrtf(fmaxf(ssx, 1e-12f));
      const float idy_ = rsqrtf(fmaxf(d0 * d0 + d1 * d1, 1e-12f));
      if (lane < BR) {   // identical values from all waves: benign
#pragma unroll
        for (int m = 0; m < 4; ++m) s_prior2[p ^ 1][rl][m] = np[m];
        s_d2[p ^ 1][rl][0] = d0;
        s_d2[p ^ 1][rl][1] = d1;
        const float n0 = d0 * idy_, n1 = d1 * idy_;
        s_in8T[0][rl] = n0; s_in8T[1][rl] = n1;
        s_in8T[2][rl] = n0; s_in8T[3][rl] = n1;
#pragma unroll
        for (int m = 0; m < 4; ++m) s_in8T[4 + m][rl] = dx[m] * idx_;
      }
    }
    {   // ---- W1-GEMM: a1 = relu([in8,1] @ [W1;b1]); tiles w,w+8,w+16[,w+24] ----
      f16x8 ah0 = f16x8_zero(), al0 = f16x8_zero();
      const int g = lane >> 4, c = lane & 15;
      if (g == 0) {
#pragma unroll
        for (int i = 0; i < 8; ++i) {
          const float v0 = s_in8T[i][c];
          const _Float16 h0 = (_Float16)v0;
          ah0[i] = h0; al0[i] = (_Float16)(v0 - (float)h0);
        }
      } else if (g == 1) {
        ah0[0] = (_Float16)1.f;   // ones-row k=8 -> b1
      }
      f32x4 p0 = {0.f, 0.f, 0.f, 0.f}, p1 = p0, p2 = p0, p3 = p0;
      const f16x8 wa = *(const f16x8*)&g_w1[(size_t)wid * 512 + ab];
      const f16x8 wb = *(const f16x8*)&g_w1[(size_t)(wid + 8) * 512 + ab];
      const f16x8 wc = *(const f16x8*)&g_w1[(size_t)(wid + 16) * 512 + ab];
      p0 = MFMA16(ah0, wa, p0); p0 = MFMA16(al0, wa, p0);
      p1 = MFMA16(ah0, wb, p1); p1 = MFMA16(al0, wb, p1);
      p2 = MFMA16(ah0, wc, p2); p2 = MFMA16(al0, wc, p2);
      if (wid < 6) {
        const f16x8 wd = *(const f16x8*)&g_w1[(size_t)(wid + 24) * 512 + ab];
        p3 = MFMA16(ah0, wd, p3); p3 = MFMA16(al0, wd, p3);
      }
#define ASTORE(A0, COLBASE)                                          \
      { const int col = (COLBASE) + (lane & 15);                     \
        _Pragma("unroll")                                            \
        for (int reg = 0; reg < 4; ++reg) {                          \
          const float v0 = fmaxf(A0[reg], 0.f);                      \
          const int o0 = afrag_off(col, g4 + reg);                   \
          const _Float16 q0 = (_Float16)v0;                          \
          sAhi[o0] = q0; sAlo[o0] = (_Float16)(v0 - (float)q0);      \
        } }
      ASTORE(p0, wid * 16)
      ASTORE(p1, (wid + 8) * 16)
      ASTORE(p2, (wid + 16) * 16)
      if (wid < 6) ASTORE(p3, (wid + 24) * 16)
    }
    __syncthreads();

    // == phase C: gates GEMM; waves 0-4 own j-tiles {w, w+8}, 5-7 own {w} ==
    f32x4 z0a = {0.f, 0.f, 0.f, 0.f}, r0a = z0a, x0a = z0a, h0a = z0a;
    f32x4 z1a = z0a, r1a = z0a, x1a = z0a, h1a = z0a;
    const bool two = (wid < 5);
    {
      const int t0 = wid, t1 = wid + 8;
      const _Float16* bz0 = g_wcat + ((size_t)(0  + t0) * KTG) * 512 + ab;
      const _Float16* br0 = g_wcat + ((size_t)(13 + t0) * KTG) * 512 + ab;
      const _Float16* bx0 = g_wcat + ((size_t)(26 + t0) * KTG) * 512 + ab;
      const _Float16* bh0 = g_wcat + ((size_t)(39 + t0) * KTG) * 512 + ab;
      const _Float16* bz1 = g_wcat + ((size_t)(0  + t1) * KTG) * 512 + ab;
      const _Float16* br1 = g_wcat + ((size_t)(13 + t1) * KTG) * 512 + ab;
      const _Float16* bx1 = g_wcat + ((size_t)(26 + t1) * KTG) * 512 + ab;
      const _Float16* bh1 = g_wcat + ((size_t)(39 + t1) * KTG) * 512 + ab;
#pragma unroll
      for (int kt = 0; kt < KTG; ++kt) {
        const int _o = kt * 512 + ab;
        const f16x8 ah = *(const f16x8*)&sAhi[_o];
        const f16x8 al = *(const f16x8*)&sAlo[_o];
        const f16x8 b0z = *(const f16x8*)(bz0 + kt * 512);
        const f16x8 b0r = *(const f16x8*)(br0 + kt * 512);
        const f16x8 b0x = (kt < 15) ? *(const f16x8*)(bx0 + kt * 512)
                                    : *(const f16x8*)(bh0 + kt * 512);
        z0a = MFMA16(ah, b0z, z0a); z0a = MFMA16(al, b0z, z0a);
        r0a = MFMA16(ah, b0r, r0a); r0a = MFMA16(al, b0r, r0a);
        if (kt < 15) { x0a = MFMA16(ah, b0x, x0a); x0a = MFMA16(al, b0x, x0a); }
        else         { h0a = MFMA16(ah, b0x, h0a); h0a = MFMA16(al, b0x, h0a); }
        if (two) {
          const f16x8 b1z = *(const f16x8*)(bz1 + kt * 512);
          const f16x8 b1r = *(const f16x8*)(br1 + kt * 512);
          const f16x8 b1x = (kt < 15) ? *(const f16x8*)(bx1 + kt * 512)
                                      : *(const f16x8*)(bh1 + kt * 512);
          z1a = MFMA16(ah, b1z, z1a); z1a = MFMA16(al, b1z, z1a);
          r1a = MFMA16(ah, b1r, r1a); r1a = MFMA16(al, b1r, r1a);
          if (kt < 15) { x1a = MFMA16(ah, b1x, x1a); x1a = MFMA16(al, b1x, x1a); }
          else         { h1a = MFMA16(ah, b1x, h1a); h1a = MFMA16(al, b1x, h1a); }
        }
      }
    }
    __syncthreads();   // all h reads done before in-place h update

    // ================= phase D': in-register GRU update =================
    {
      const int c = lane & 15;
#define GRU1(AZ, AR, AX, AH, J)                                          \
      { const float bz  = s_bias[0][J], brb = s_bias[1][J];              \
        const float bxh = s_bias[2][J], bhh = s_bias[3][J];              \
        _Pragma("unroll")                                                \
        for (int reg = 0; reg < 4; ++reg) {                              \
          const int r = g4 + reg;                                        \
          const int off = afrag_off(480 + (J), r);                       \
          const float hold = (float)sAhi[off] + (float)sAlo[off];        \
          const float z  = sigmoid_(AZ[reg] + bz);                       \
          const float rr = sigmoid_(AR[reg] + brb);                      \
          const float hc = tanh_((AX[reg] + bxh) + rr * (AH[reg] + bhh));\
          const float hn = z * hold + (1.f - z) * hc;                    \
          const _Float16 qh = (_Float16)hn;                              \
          sAhi[off] = qh;                                                \
          sAlo[off] = (_Float16)(hn - (float)qh);                       \
        } }
      const int j0 = wid * 16 + c;            // <= 127 < 200: no guard
      GRU1(z0a, r0a, x0a, h0a, j0)
      if (two) {
        const int j1 = (wid + 8) * 16 + c;    // <= 207: guard tile 12 tail
        if (j1 < HID) GRU1(z1a, r1a, x1a, h1a, j1)
      }
#undef GRU1
    }
    __syncthreads();

    // == phase E: a2 = relu(h @ W2 + b2); tiles w, w+8 [, w+16 for w<4] ==
    {
      f32x4 e0 = {0.f, 0.f, 0.f, 0.f}, e1 = e0, e2 = e0;
      const bool three = (wid < 4);
      const _Float16* w2a = g_w2 + ((size_t)wid * KT2) * 512 + ab;
      const _Float16* w2b = g_w2 + ((size_t)(wid + 8) * KT2) * 512 + ab;
      const _Float16* w2c = g_w2 + ((size_t)(wid + 16) * KT2) * 512 + ab;
#pragma unroll
      for (int qt = 0; qt < KT2; ++qt) {
        const int _o = (15 + qt) * 512 + ab;
        const f16x8 ah = *(const f16x8*)&sAhi[_o];
        const f16x8 al = *(const f16x8*)&sAlo[_o];
        const f16x8 ba = *(const f16x8*)(w2a + qt * 512);
        const f16x8 bb = *(const f16x8*)(w2b + qt * 512);
        e0 = MFMA16(ah, ba, e0); e0 = MFMA16(al, ba, e0);
        e1 = MFMA16(ah, bb, e1); e1 = MFMA16(al, bb, e1);
        if (three) {
          const f16x8 bc = *(const f16x8*)(w2c + qt * 512);
          e2 = MFMA16(ah, bc, e2); e2 = MFMA16(al, bc, e2);
        }
      }
      ASTORE(e0, wid * 16)
      ASTORE(e1, (wid + 8) * 16)
      if (three) ASTORE(e2, (wid + 16) * 16)
#undef ASTORE
    }
    __syncthreads();

    // ========== phase F: KG partials (waves 0,1 = k-halves) ==========
    if (wid < 2) {
      const int half = wid;
      f32x4 ka = {0.f, 0.f, 0.f, 0.f};
      const _Float16* w3p = g_w3 + ab;
#pragma unroll
      for (int q = 0; q < 5; ++q) {
        const int kt3 = half * 5 + q;
        const int _o = kt3 * 512 + ab;
        const f16x8 ah = *(const f16x8*)&sAhi[_o];
        const f16x8 al = *(const f16x8*)&sAlo[_o];
        const f16x8 bw = *(const f16x8*)(w3p + kt3 * 512);
        ka = MFMA16(ah, bw, ka); ka = MFMA16(al, bw, ka);
      }
      const int c = lane & 15;
      if (c < 8) {
#pragma unroll
        for (int reg = 0; reg < 4; ++reg) s_kgp[half][g4 + reg][c] = ka[reg];
      }
    }
    __syncthreads();
  }

  // ---- final F2 (t = T_STEPS, parity 0) ----
  {
    float kg[8];
#pragma unroll
    for (int cc = 0; cc < 8; ++cc)
      kg[cc] = s_kgp[0][rl][cc] + s_kgp[1][rl][cc] + s_b3[cc];
    const float pd0 = s_d2[0][rl][0], pd1 = s_d2[0][rl][1];
    if (wid == 0 && lane < BR) {
      float4 o;
      o.x = s_prior2[0][rl][0] + kg[0] * pd0 + kg[1] * pd1;
      o.y = s_prior2[0][rl][1] + kg[2] * pd0 + kg[3] * pd1;
      o.z = s_prior2[0][rl][2] + kg[4] * pd0 + kg[5] * pd1;
      o.w = s_prior2[0][rl][3] + kg[6] * pd0 + kg[7] * pd1;
      *(float4*)&out[((size_t)(T_STEPS - 1) * BATCH + row0 + rl) * 4] = o;
    }
  }
}

}  // namespace

extern "C" void kernel_launch(void* const* d_in, const int* in_sizes, int n_in,
                              void* d_out, int out_size, void* d_ws, size_t ws_size,
                              hipStream_t stream) {
  const float* y   = (const float*)d_in[0];
  const float* Fm  = (const float*)d_in[1];
  const float* Hm  = (const float*)d_in[2];
  const float* W1  = (const float*)d_in[3];
  const float* b1  = (const float*)d_in[4];
  const float* Wg  = (const float*)d_in[5];
  const float* Ug  = (const float*)d_in[6];
  const float* bg  = (const float*)d_in[7];
  const float* W2  = (const float*)d_in[8];
  const float* b2  = (const float*)d_in[9];
  const float* W3  = (const float*)d_in[10];
  const float* b3  = (const float*)d_in[11];
  const float* hn0 = (const float*)d_in[12];
  float* out = (float*)d_out;

  constexpr int PREP_TOT = (NTW1 + NTG * KTG + NT2 * KT2 + KT3) * 512;
  prep_kernel<<<(PREP_TOT + 255) / 256, 256, 0, stream>>>(W1, b1, Wg, Ug, W2, b2, W3);
  knet_kernel<<<BATCH / BR, NTHR, 0, stream>>>(y, Fm, Hm, bg, b3, hn0, out);
}

// Round 11
// 1880.024 us; speedup vs baseline: 1.2706x; 1.2706x over previous
//
#include <hip/hip_runtime.h>

// KalmanNet recurrent step, MFMA fp16, r11: BR=64 -- halve total weight traffic.
//
// r10 post-mortem: time scales with total weight traffic (r8 1.96GB/1349us,
// r10 2.97GB/2323us, both ~1.4GB/ms) => the kernel is weight-traffic-bound
// on the shared L2-miss path, not barrier-latency-bound. r11 inverts r10:
// 128 blocks x 64 rows (4 MFMA m-tiles), each block amortizes the per-step
// 1.2 MB weight read over 2x the rows => chip-total traffic halves.
//
// Precision budget (LDS forces it): a1/a2 stored single-fp16 (their quant
// error reaches the output only through KG = a2@W3 with W3~0.02 scale =>
// ~1e-5/step); h (recurrent, accumulating) keeps exact hi/lo fp16 split.
// LDS: sA1 60KB + sAh hi/lo 2x28KB + state ~12KB = ~131KB, 1 block/CU.
//
// Work split (16 waves): gates: waves 0..12 own j-tile w of each group
// {z,r,xh,hh} for all 4 m-groups (acc = 16 f32x4 = 64 AGPR); W1: tiles
// {w, w+16 if w<14}; W2: {w, w+16 if w<4}; W3: waves 0..7 = (mg, k-half).
// GRU in registers; h in sAh slots k_h=j. State in parity LDS (r8).
// Bias folding: W1 ones-row k=8 -> b1; h-pad k_h=200==1.0 carries b2 via
// g_w2 row 200 (gate weights there are zero).
//
// Fragment maps (verified r2-r10): A/B k = kt*32 + (lane>>4)*8 + i,
// A row / B col = lane&15; C/D col = lane&15, row = (lane>>4)*4 + reg.

namespace {

constexpr int T_STEPS = 32;
constexpr int BATCH   = 8192;
constexpr int H1      = 480;
constexpr int HID     = 200;
constexpr int H2      = 320;
constexpr int BR      = 64;    // batch rows per block (4 MFMA m-tiles)
constexpr int NTHR    = 1024;  // 16 waves, 4/SIMD, 1 block/CU
constexpr int KTG     = 22;    // gates K tiles (704 = 480 a1 + 224 h/pad)
constexpr int KTA     = 15;    // a1 K tiles (480)
constexpr int NTG     = 52;    // 4 groups x 13 real j-tiles
constexpr int NTW1    = 30;    // W1 real col tiles (480/16)
constexpr int NT2     = 20;    // W2 real col tiles (320/16)
constexpr int KT2     = 7;     // W2 K tiles (224)
constexpr int KT3     = 10;    // W3 K tiles (320)

using f16x8 = __attribute__((ext_vector_type(8))) _Float16;
using f32x4 = __attribute__((ext_vector_type(4))) float;

__device__ _Float16 g_w1[NTW1 * 512];          // [nt][lane][8], k=8 row = b1
__device__ _Float16 g_wcat[NTG * KTG * 512];   // [grp*13+tile][kt][lane][8]
__device__ _Float16 g_w2[NT2 * KT2 * 512];     // [nt][kt][lane][8], k_h=200 = b2
__device__ _Float16 g_w3[KT3 * 512];           // [kt][lane][8], cols 8..15 = 0

#define MFMA16(A, B, C) __builtin_amdgcn_mfma_f32_16x16x32_f16((A), (B), (C), 0, 0, 0)

__device__ __forceinline__ float sigmoid_(float x) { return 1.f / (1.f + __expf(-x)); }
__device__ __forceinline__ float tanh_(float x) {
  x = fminf(fmaxf(x, -15.f), 15.f);
  const float e = __expf(-2.f * x);
  return (1.f - e) / (1.f + e);
}
__device__ __forceinline__ f16x8 f16x8_zero() {
  f16x8 v;
#pragma unroll
  for (int i = 0; i < 8; ++i) v[i] = (_Float16)0.f;
  return v;
}

// A-fragment LDS index: [kt][mg][lane = ((kk>>3)<<4)|r15][i = kk&7]
__device__ __forceinline__ int idxA(int kt, int mg, int r15, int kk) {
  return kt * 2048 + mg * 512 + ((((kk >> 3) << 4) | r15) * 8) + (kk & 7);
}

// ---------------- weight pre-pack (identical to r10) ----------------
__global__ __launch_bounds__(256) void prep_kernel(
    const float* __restrict__ W1, const float* __restrict__ b1,
    const float* __restrict__ Wg, const float* __restrict__ Ug,
    const float* __restrict__ W2, const float* __restrict__ b2,
    const float* __restrict__ W3) {
  const int idx = blockIdx.x * 256 + threadIdx.x;
  constexpr int TOTW1 = NTW1 * 512;
  constexpr int TOT1  = NTG * KTG * 512;
  constexpr int TOT2  = NT2 * KT2 * 512;
  constexpr int TOT3  = KT3 * 512;
  if (idx < TOTW1) {
    const int i = idx & 7, l = (idx >> 3) & 63, nt = idx >> 9;
    const int g = l >> 4, c = l & 15;
    const int k = g * 8 + i, col = nt * 16 + c;   // col < 480 always
    float wv = 0.f;
    if (k < 8) wv = W1[k * H1 + col];
    else if (k == 8) wv = b1[col];
    g_w1[idx] = (_Float16)wv;
  } else if (idx < TOTW1 + TOT1) {
    const int id = idx - TOTW1;
    const int i = id & 7, l = (id >> 3) & 63, nk = id >> 9;
    const int kt = nk % KTG, nt = nk / KTG;
    const int g = l >> 4, c = l & 15;
    const int k = kt * 32 + g * 8 + i;        // 0..703
    const int grp = nt / 13;                  // 0=z 1=r 2=xh 3=hh
    const int jj = (nt - grp * 13) * 16 + c;  // 0..207
    float wv = 0.f;
    if (jj < HID) {
      if (grp == 0) {
        if (k < H1) wv = Wg[k * 600 + jj];
        else if (k < H1 + HID) wv = Ug[(k - H1) * 600 + jj];
      } else if (grp == 1) {
        if (k < H1) wv = Wg[k * 600 + 200 + jj];
        else if (k < H1 + HID) wv = Ug[(k - H1) * 600 + 200 + jj];
      } else if (grp == 2) {
        if (k < H1) wv = Wg[k * 600 + 400 + jj];           // xh: a1 rows only
      } else {
        if (k >= H1 && k < H1 + HID) wv = Ug[(k - H1) * 600 + 400 + jj];  // hh
      }
    }
    g_wcat[id] = (_Float16)wv;
  } else if (idx < TOTW1 + TOT1 + TOT2) {
    const int id = idx - TOTW1 - TOT1;
    const int i = id & 7, l = (id >> 3) & 63, nk = id >> 9;
    const int kt = nk % KT2, nt = nk / KT2;
    const int g = l >> 4, c = l & 15;
    const int k = kt * 32 + g * 8 + i;        // 0..223
    const int col = nt * 16 + c;              // 0..319 (all real)
    float wv = 0.f;
    if (k < HID) wv = W2[k * H2 + col];
    else if (k == 200) wv = b2[col];          // ones-row at k_h=200
    g_w2[id] = (_Float16)wv;
  } else if (idx < TOTW1 + TOT1 + TOT2 + TOT3) {
    const int id = idx - TOTW1 - TOT1 - TOT2;
    const int i = id & 7, l = (id >> 3) & 63, kt = id >> 9;
    const int g = l >> 4, c = l & 15;
    const int k = kt * 32 + g * 8 + i;        // 0..319
    g_w3[id] = (_Float16)((c < 8) ? W3[k * 8 + c] : 0.f);
  }
}

// ---------------- main recurrent kernel ----------------
__global__
__attribute__((amdgpu_flat_work_group_size(NTHR, NTHR)))
__attribute__((amdgpu_waves_per_eu(4, 4)))
void knet_kernel(
    const float* __restrict__ y,    // [T,B,2]
    const float* __restrict__ Fm,   // [4,4]
    const float* __restrict__ Hm,   // [2,4]
    const float* __restrict__ bg,   // [2,600]
    const float* __restrict__ b3,   // [8]
    const float* __restrict__ hn0,  // [B,200]
    float* __restrict__ out)        // [T,B,4]
{
  // a1 (k 0..479) single fp16; slots 0..9 reused for a2 (cols 0..319) E->F
  __shared__ alignas(16) _Float16 sA1[KTA * 4 * 512];    // 61440 B
  // h region (k_h 0..223 incl. 1.0@200 pad), exact hi/lo
  __shared__ alignas(16) _Float16 sAhh[KT2 * 4 * 512];   // 28672 B
  __shared__ alignas(16) _Float16 sAhl[KT2 * 4 * 512];   // 28672 B
  __shared__ alignas(16) float s_in8T[8][BR];
  __shared__ alignas(16) float s_kgp[2][BR][8];          // KG k-half partials
  __shared__ alignas(16) float s_bias[4][HID];
  __shared__ alignas(16) float s_fh[32];                 // Fm[16], Hm[8]
  __shared__ alignas(16) float s_b3[8];
  __shared__ alignas(16) float s_prior2[2][BR][4];       // t-parity state
  __shared__ alignas(16) float s_d2[2][BR][2];

  const int tid  = threadIdx.x;
  const int lane = tid & 63;
  const int wid  = __builtin_amdgcn_readfirstlane(tid >> 6);  // 0..15
  const int row0 = blockIdx.x * BR;
  const int g4   = (lane >> 4) << 2;
  const int ab   = lane * 8;
  const int c16  = lane & 15;

  // ---- init ----
  if (tid < HID) {
    s_bias[0][tid] = bg[tid]       + bg[600 + tid];   // z
    s_bias[1][tid] = bg[200 + tid] + bg[800 + tid];   // r
    s_bias[2][tid] = bg[400 + tid];                   // xh (input bias)
    s_bias[3][tid] = bg[1000 + tid];                  // hh (recurrent bias)
  }
  if (tid < 16) s_fh[tid] = Fm[tid];
  else if (tid < 24) s_fh[tid] = Hm[tid - 16];
  if (tid < 8) s_b3[tid] = b3[tid];
  if (tid < BR * 4) s_prior2[0][tid >> 2][tid & 3] = 0.f;
  if (tid < BR * 2) s_d2[0][tid >> 1][tid & 1] = 0.f;
  for (int e = tid; e < HID * BR; e += NTHR) {          // hn0 -> hi/lo
    const int j = e >> 6, r = e & 63;
    const float h0 = hn0[(size_t)(row0 + r) * HID + j];
    const int off = idxA(j >> 5, r >> 4, r & 15, j & 31);
    const _Float16 hi = (_Float16)h0;
    sAhh[off] = hi;
    sAhl[off] = (_Float16)(h0 - (float)hi);
  }
  for (int e = tid; e < 24 * BR; e += NTHR) {           // k_h 200..223 pad
    const int kh = 200 + (e >> 6), r = e & 63;
    const int off = idxA(kh >> 5, r >> 4, r & 15, kh & 31);
    sAhh[off] = (_Float16)((kh == 200) ? 1.f : 0.f);
    sAhl[off] = (_Float16)0.f;
  }
  __syncthreads();

  for (int t = 0; t < T_STEPS; ++t) {
    const int p = t & 1;
    // ============== phase 1: F2(t-1) + A(t) + W1-GEMM(t) ==============
    {
      const int rl = lane;                  // 64 lanes = 64 rows
      float post[4] = {0.f, 0.f, 0.f, 0.f};
      if (t > 0) {
        float kg[8];
#pragma unroll
        for (int cc = 0; cc < 8; ++cc)
          kg[cc] = s_kgp[0][rl][cc] + s_kgp[1][rl][cc] + s_b3[cc];
        const float pd0 = s_d2[p][rl][0], pd1 = s_d2[p][rl][1];
#pragma unroll
        for (int m = 0; m < 4; ++m)
          post[m] = s_prior2[p][rl][m] + kg[2 * m] * pd0 + kg[2 * m + 1] * pd1;
        if (wid == 0) {
          float4 o; o.x = post[0]; o.y = post[1]; o.z = post[2]; o.w = post[3];
          *(float4*)&out[((size_t)(t - 1) * BATCH + row0 + rl) * 4] = o;
        }
      }
      float opri[4], np[4];
#pragma unroll
      for (int m = 0; m < 4; ++m) opri[m] = s_prior2[p][rl][m];
#pragma unroll
      for (int m = 0; m < 4; ++m) {
        float s = 0.f;
#pragma unroll
        for (int j = 0; j < 4; ++j) s += s_fh[m * 4 + j] * post[j];
        np[m] = s;
      }
      float m0 = 0.f, m1 = 0.f;
#pragma unroll
      for (int m = 0; m < 4; ++m) { m0 += s_fh[16 + m] * np[m]; m1 += s_fh[20 + m] * np[m]; }
      const float2 yv = *(const float2*)&y[((size_t)t * BATCH + row0 + rl) * 2];
      const float d0 = yv.x - m0;
      const float d1 = yv.y - m1;
      float dx[4], ssx = 0.f;
#pragma unroll
      for (int m = 0; m < 4; ++m) { dx[m] = post[m] - opri[m]; ssx += dx[m] * dx[m]; }
      const float idx_ = rsqrtf(fmaxf(ssx, 1e-12f));
      const float idy_ = rsqrtf(fmaxf(d0 * d0 + d1 * d1, 1e-12f));
      // identical values from all waves: benign duplicate writes
#pragma unroll
      for (int m = 0; m < 4; ++m) s_prior2[p ^ 1][rl][m] = np[m];
      s_d2[p ^ 1][rl][0] = d0;
      s_d2[p ^ 1][rl][1] = d1;
      const float n0 = d0 * idy_, n1 = d1 * idy_;
      s_in8T[0][rl] = n0; s_in8T[1][rl] = n1;
      s_in8T[2][rl] = n0; s_in8T[3][rl] = n1;
#pragma unroll
      for (int m = 0; m < 4; ++m) s_in8T[4 + m][rl] = dx[m] * idx_;
    }
    {   // ---- W1-GEMM: a1 = relu([in8,1] @ [W1;b1]); tiles w [, w+16] ----
      const int g = lane >> 4;
      f16x8 ih[4], il[4];
#pragma unroll
      for (int mg = 0; mg < 4; ++mg) { ih[mg] = f16x8_zero(); il[mg] = f16x8_zero(); }
      if (g == 0) {
#pragma unroll
        for (int mg = 0; mg < 4; ++mg)
#pragma unroll
          for (int i = 0; i < 8; ++i) {
            const float v = s_in8T[i][mg * 16 + c16];
            const _Float16 h = (_Float16)v;
            ih[mg][i] = h; il[mg][i] = (_Float16)(v - (float)h);
          }
      } else if (g == 1) {
#pragma unroll
        for (int mg = 0; mg < 4; ++mg) ih[mg][0] = (_Float16)1.f;  // b1 row
      }
      const bool hasB = (wid < 14);
      const f16x8 wa = *(const f16x8*)&g_w1[(size_t)wid * 512 + ab];
      f32x4 pa[4], pb[4];
#pragma unroll
      for (int mg = 0; mg < 4; ++mg) {
        pa[mg] = f32x4{0.f, 0.f, 0.f, 0.f};
        pb[mg] = f32x4{0.f, 0.f, 0.f, 0.f};
        pa[mg] = MFMA16(ih[mg], wa, pa[mg]);
        pa[mg] = MFMA16(il[mg], wa, pa[mg]);
      }
      if (hasB) {
        const f16x8 wb = *(const f16x8*)&g_w1[(size_t)(wid + 16) * 512 + ab];
#pragma unroll
        for (int mg = 0; mg < 4; ++mg) {
          pb[mg] = MFMA16(ih[mg], wb, pb[mg]);
          pb[mg] = MFMA16(il[mg], wb, pb[mg]);
        }
      }
      const int col0 = wid * 16 + c16;
      const int col1 = (wid + 16) * 16 + c16;
#pragma unroll
      for (int mg = 0; mg < 4; ++mg)
#pragma unroll
        for (int reg = 0; reg < 4; ++reg) {
          sA1[idxA(col0 >> 5, mg, g4 + reg, col0 & 31)] =
              (_Float16)fmaxf(pa[mg][reg], 0.f);
          if (hasB)
            sA1[idxA(col1 >> 5, mg, g4 + reg, col1 & 31)] =
                (_Float16)fmaxf(pb[mg][reg], 0.f);
        }
    }
    __syncthreads();

    // ===== phase C: gates GEMM; wave w<13 owns j-tile w of each group =====
    f32x4 az[4], ar_[4], ax[4], ah_[4];
#pragma unroll
    for (int mg = 0; mg < 4; ++mg) {
      az[mg] = f32x4{0.f, 0.f, 0.f, 0.f}; ar_[mg] = az[mg];
      ax[mg] = az[mg]; ah_[mg] = az[mg];
    }
    if (wid < 13) {
      const _Float16* bz = g_wcat + ((size_t)(0  + wid) * KTG) * 512 + ab;
      const _Float16* br = g_wcat + ((size_t)(13 + wid) * KTG) * 512 + ab;
      const _Float16* bx = g_wcat + ((size_t)(26 + wid) * KTG) * 512 + ab;
      const _Float16* bh = g_wcat + ((size_t)(39 + wid) * KTG) * 512 + ab;
#pragma unroll
      for (int kt = 0; kt < KTG; ++kt) {
        const f16x8 vz = *(const f16x8*)(bz + kt * 512);
        const f16x8 vr = *(const f16x8*)(br + kt * 512);
        const f16x8 vx = (kt < KTA) ? *(const f16x8*)(bx + kt * 512)
                                    : *(const f16x8*)(bh + kt * 512);
        if (kt < KTA) {           // a1 region: single fp16 A
#pragma unroll
          for (int mg = 0; mg < 4; ++mg) {
            const f16x8 a = *(const f16x8*)&sA1[kt * 2048 + mg * 512 + ab];
            az[mg]  = MFMA16(a, vz, az[mg]);
            ar_[mg] = MFMA16(a, vr, ar_[mg]);
            ax[mg]  = MFMA16(a, vx, ax[mg]);
          }
        } else {                  // h region: hi/lo A
          const int kh = kt - KTA;
#pragma unroll
          for (int mg = 0; mg < 4; ++mg) {
            const f16x8 ahi = *(const f16x8*)&sAhh[kh * 2048 + mg * 512 + ab];
            const f16x8 alo = *(const f16x8*)&sAhl[kh * 2048 + mg * 512 + ab];
            az[mg]  = MFMA16(ahi, vz, az[mg]);  az[mg]  = MFMA16(alo, vz, az[mg]);
            ar_[mg] = MFMA16(ahi, vr, ar_[mg]); ar_[mg] = MFMA16(alo, vr, ar_[mg]);
            ah_[mg] = MFMA16(ahi, vx, ah_[mg]); ah_[mg] = MFMA16(alo, vx, ah_[mg]);
          }
        }
      }
    }
    __syncthreads();   // all h reads done before in-place h update

    // ================= phase D: in-register GRU update =================
    if (wid < 13) {
      const int j = wid * 16 + c16;
      if (j < HID) {
        const float bz4 = s_bias[0][j], brb = s_bias[1][j];
        const float bxh = s_bias[2][j], bhh = s_bias[3][j];
        const int kth = j >> 5, kk = j & 31;
#pragma unroll
        for (int mg = 0; mg < 4; ++mg)
#pragma unroll
          for (int reg = 0; reg < 4; ++reg) {
            const int off = idxA(kth, mg, g4 + reg, kk);
            const float hold = (float)sAhh[off] + (float)sAhl[off];
            const float z  = sigmoid_(az[mg][reg] + bz4);
            const float rr = sigmoid_(ar_[mg][reg] + brb);
            const float hc = tanh_((ax[mg][reg] + bxh) + rr * (ah_[mg][reg] + bhh));
            const float hn = z * hold + (1.f - z) * hc;
            const _Float16 qh = (_Float16)hn;
            sAhh[off] = qh;
            sAhl[off] = (_Float16)(hn - (float)qh);
          }
      }
    }
    __syncthreads();

    // ======= phase E: a2 = relu(h @ W2 + b2); tiles w [, w+16 if w<4] =======
    {
      const bool h2 = (wid < 4);
      f32x4 e0[4], e1[4];
#pragma unroll
      for (int mg = 0; mg < 4; ++mg) {
        e0[mg] = f32x4{0.f, 0.f, 0.f, 0.f};
        e1[mg] = f32x4{0.f, 0.f, 0.f, 0.f};
      }
      const _Float16* w2a = g_w2 + ((size_t)wid * KT2) * 512 + ab;
      const _Float16* w2b = g_w2 + ((size_t)(wid + 16) * KT2) * 512 + ab;
#pragma unroll
      for (int qt = 0; qt < KT2; ++qt) {
        const f16x8 ba = *(const f16x8*)(w2a + qt * 512);
#pragma unroll
        for (int mg = 0; mg < 4; ++mg) {
          const f16x8 ahi = *(const f16x8*)&sAhh[qt * 2048 + mg * 512 + ab];
          const f16x8 alo = *(const f16x8*)&sAhl[qt * 2048 + mg * 512 + ab];
          e0[mg] = MFMA16(ahi, ba, e0[mg]);
          e0[mg] = MFMA16(alo, ba, e0[mg]);
        }
        if (h2) {
          const f16x8 bb = *(const f16x8*)(w2b + qt * 512);
#pragma unroll
          for (int mg = 0; mg < 4; ++mg) {
            const f16x8 ahi = *(const f16x8*)&sAhh[qt * 2048 + mg * 512 + ab];
            const f16x8 alo = *(const f16x8*)&sAhl[qt * 2048 + mg * 512 + ab];
            e1[mg] = MFMA16(ahi, bb, e1[mg]);
            e1[mg] = MFMA16(alo, bb, e1[mg]);
          }
        }
      }
      // a2 -> sA1 slots 0..9, single fp16 (b2 folded via ones-row)
      const int col0 = wid * 16 + c16;
      const int col1 = (wid + 16) * 16 + c16;
#pragma unroll
      for (int mg = 0; mg < 4; ++mg)
#pragma unroll
        for (int reg = 0; reg < 4; ++reg) {
          sA1[idxA(col0 >> 5, mg, g4 + reg, col0 & 31)] =
              (_Float16)fmaxf(e0[mg][reg], 0.f);
          if (h2)
            sA1[idxA(col1 >> 5, mg, g4 + reg, col1 & 31)] =
                (_Float16)fmaxf(e1[mg][reg], 0.f);
        }
    }
    __syncthreads();

    // ===== phase F: KG partials; waves 0..7 = (m-group, k-half) =====
    if (wid < 8) {
      const int mg = wid >> 1, half = wid & 1;
      f32x4 ka = {0.f, 0.f, 0.f, 0.f};
#pragma unroll
      for (int q = 0; q < 5; ++q) {
        const int kt3 = half * 5 + q;
        const f16x8 a  = *(const f16x8*)&sA1[kt3 * 2048 + mg * 512 + ab];
        const f16x8 bw = *(const f16x8*)&g_w3[kt3 * 512 + ab];
        ka = MFMA16(a, bw, ka);
      }
      if (c16 < 8) {
#pragma unroll
        for (int reg = 0; reg < 4; ++reg)
          s_kgp[half][mg * 16 + g4 + reg][c16] = ka[reg];
      }
    }
    __syncthreads();
  }

  // ---- final F2 (t = T_STEPS, parity 0) ----
  {
    const int rl = lane;
    float kg[8];
#pragma unroll
    for (int cc = 0; cc < 8; ++cc)
      kg[cc] = s_kgp[0][rl][cc] + s_kgp[1][rl][cc] + s_b3[cc];
    const float pd0 = s_d2[0][rl][0], pd1 = s_d2[0][rl][1];
    if (wid == 0) {
      float4 o;
      o.x = s_prior2[0][rl][0] + kg[0] * pd0 + kg[1] * pd1;
      o.y = s_prior2[0][rl][1] + kg[2] * pd0 + kg[3] * pd1;
      o.z = s_prior2[0][rl][2] + kg[4] * pd0 + kg[5] * pd1;
      o.w = s_prior2[0][rl][3] + kg[6] * pd0 + kg[7] * pd1;
      *(float4*)&out[((size_t)(T_STEPS - 1) * BATCH + row0 + rl) * 4] = o;
    }
  }
}

}  // namespace

extern "C" void kernel_launch(void* const* d_in, const int* in_sizes, int n_in,
                              void* d_out, int out_size, void* d_ws, size_t ws_size,
                              hipStream_t stream) {
  const float* y   = (const float*)d_in[0];
  const float* Fm  = (const float*)d_in[1];
  const float* Hm  = (const float*)d_in[2];
  const float* W1  = (const float*)d_in[3];
  const float* b1  = (const float*)d_in[4];
  const float* Wg  = (const float*)d_in[5];
  const float* Ug  = (const float*)d_in[6];
  const float* bg  = (const float*)d_in[7];
  const float* W2  = (const float*)d_in[8];
  const float* b2  = (const float*)d_in[9];
  const float* W3  = (const float*)d_in[10];
  const float* b3  = (const float*)d_in[11];
  const float* hn0 = (const float*)d_in[12];
  float* out = (float*)d_out;

  constexpr int PREP_TOT = (NTW1 + NTG * KTG + NT2 * KT2 + KT3) * 512;
  prep_kernel<<<(PREP_TOT + 255) / 256, 256, 0, stream>>>(W1, b1, Wg, Ug, W2, b2, W3);
  knet_kernel<<<BATCH / BR, NTHR, 0, stream>>>(y, Fm, Hm, bg, b3, hn0, out);
}